// Round 12
// baseline (323.347 us; speedup 1.0000x reference)
//
#include <hip/hip_runtime.h>
#include <hip/hip_bf16.h>

typedef short bf16x8 __attribute__((ext_vector_type(8)));
typedef float f32x4 __attribute__((ext_vector_type(4)));
typedef float f32x2 __attribute__((ext_vector_type(2)));
typedef unsigned int u32x4 __attribute__((ext_vector_type(4)));

#define MFMA(a, b, c) __builtin_amdgcn_mfma_f32_16x16x32_bf16((a), (b), (c), 0, 0, 0)

__device__ __forceinline__ unsigned short f2bf(float f) {
    unsigned u = __builtin_bit_cast(unsigned, f);
    unsigned r = u + 0x7FFFu + ((u >> 16) & 1u);   // RNE
    return (unsigned short)(r >> 16);
}

// pair of f32 -> packed bf16 dword (v_cvt_pk_bf16_f32)
__device__ __forceinline__ unsigned pk_bf16(float lo, float hi) {
    __hip_bfloat162 p = __float22bfloat162_rn(make_float2(lo, hi));
    unsigned r;
    __builtin_memcpy(&r, &p, sizeof(r));
    return r;
}

__device__ __forceinline__ float sigm(float x) {
    float e = __builtin_amdgcn_exp2f(-1.44269504088896f * x);
    return __builtin_amdgcn_rcpf(1.0f + e);
}

__device__ __forceinline__ f32x2 exp2v(f32x2 v) {
    f32x2 r;
    r.x = __builtin_amdgcn_exp2f(v.x);
    r.y = __builtin_amdgcn_exp2f(v.y);
    return r;
}

// R11 structure (best: 304us): one wave per 16 batches, lane-local recurrence,
// no barriers/LDS, loop-carried accx x-projection pipeline, common-denominator
// cell math (6 trans/unit: 5 exp + 1 paired rcp).
// NEW (R12): cell math on f32x2 vectors — the lane's lo/hi unit chains are
// independent and identical, so all fast-VALU ops pack into v_pk_{fma,add,mul}_f32
// (VOP3P, 2 f32/instr). exp2/rcp remain scalar (no packed trans). Arithmetic
// is bit-identical to R11 -> absmax must stay exactly 0.00390625.
__global__ __launch_bounds__(256, 1) void lstm_mfma12_kernel(
    const float* __restrict__ x,     // [B,512,3]
    const float* __restrict__ W_ih,  // [128,3]
    const float* __restrict__ W_hh,  // [128,32]
    const float* __restrict__ b_ih,  // [128]
    const float* __restrict__ b_hh,  // [128]
    const float* __restrict__ W_fc,  // [32]
    const float* __restrict__ b_fc,  // [1]
    float* __restrict__ out,         // [B]
    int n_groups)
{
    const int lane  = threadIdx.x & 63;
    const int wid   = threadIdx.x >> 6;
    const int group = blockIdx.x * 4 + wid;
    if (group >= n_groups) return;

    const int n = lane & 15;
    const int q = lane >> 4;

    const float NL2E  = -1.4426950408889634f;  // -log2(e)
    const float P2L2E =  2.8853900817779268f;  // +2*log2(e)

    // tiles: (0,1)=i, (2,3)=f, (4,5)=g, (6,7)=o ; even=units 0..15, odd=16..31
    bf16x8 A_hh[8], A_x[8];
#pragma unroll
    for (int t = 0; t < 8; ++t) {
        const int g = 16 * t + n;
        const float s = (t == 4 || t == 5) ? P2L2E : NL2E;
        bf16x8 a, ax;
#pragma unroll
        for (int j = 0; j < 8; ++j) {
            const int k = 16 * (j >> 2) + 4 * q + (j & 3);
            a[j] = (short)f2bf(s * W_hh[g * 32 + k]);
            float axv = 0.0f;
            if (q == 0 && j < 4) {
                axv = (j < 3) ? s * W_ih[g * 3 + j] : s * (b_ih[g] + b_hh[g]);
            }
            ax[j] = (short)f2bf(axv);
        }
        A_hh[t] = a;
        A_x[t]  = ax;
    }

    const long bn = (long)group * 16 + n;
    const float4* xv = (const float4*)(x + bn * (512L * 3));  // 384 float4/batch

    // state as f32x2: .x = lo unit (4q+r), .y = hi unit (16+4q+r)
    f32x2 cs2[4] = {{0.f, 0.f}, {0.f, 0.f}, {0.f, 0.f}, {0.f, 0.f}};
    f32x2 h2[4]  = {{0.f, 0.f}, {0.f, 0.f}, {0.f, 0.f}, {0.f, 0.f}};
    bf16x8 Bh = {0, 0, 0, 0, 0, 0, 0, 0};

    float4 xa = xv[0], xb = xv[1], xc = xv[2];

    // prologue: x-projection for step 0
    f32x4 accx[8];
    {
        unsigned bx01 = pk_bf16(xa.x, xa.y);
        unsigned bx23 = pk_bf16(xa.z, 1.0f);
        u32x4 bxv = {bx01, bx23, bx01, bx23};
        bf16x8 Bx = __builtin_bit_cast(bf16x8, bxv);
#pragma unroll
        for (int tt = 0; tt < 8; ++tt) {
            f32x4 z = {0.f, 0.f, 0.f, 0.f};
            accx[tt] = MFMA(A_x[tt], Bx, z);
        }
    }

    const f32x2 ONE2   = {1.0f, 1.0f};
    const f32x2 P2L2E2 = {P2L2E, P2L2E};
    const f32x2 NP2L2E2= {-P2L2E, -P2L2E};
    const f32x2 TH30   = {30.0f, 30.0f};
    const f32x2 NTWO2  = {-2.0f, -2.0f};

#define STEP(XN0, XN1, XN2)                                                     \
    do {                                                                        \
        f32x4 acc[8];                                                           \
        _Pragma("unroll")                                                       \
        for (int tt = 0; tt < 8; ++tt) acc[tt] = MFMA(A_hh[tt], Bh, accx[tt]);  \
        unsigned bx01 = pk_bf16((XN0), (XN1));                                  \
        unsigned bx23 = pk_bf16((XN2), 1.0f);                                   \
        u32x4 bxv = {bx01, bx23, bx01, bx23};                                   \
        bf16x8 Bx = __builtin_bit_cast(bf16x8, bxv);                            \
        _Pragma("unroll")                                                       \
        for (int tt = 0; tt < 8; ++tt) {                                        \
            f32x4 z = {0.f, 0.f, 0.f, 0.f};                                     \
            accx[tt] = MFMA(A_x[tt], Bx, z);                                    \
        }                                                                       \
        _Pragma("unroll")                                                       \
        for (int r = 0; r < 4; ++r) {                                           \
            f32x2 ui = exp2v(f32x2{acc[0][r], acc[1][r]});                      \
            f32x2 uf = exp2v(f32x2{acc[2][r], acc[3][r]});                      \
            f32x2 ug = exp2v(f32x2{acc[4][r], acc[5][r]});                      \
            f32x2 uo = exp2v(f32x2{acc[6][r], acc[7][r]});                      \
            f32x2 t1 = ONE2 + ui, t2 = ONE2 + ug, t3 = ONE2 + uf;               \
            f32x2 p  = t1 * t2;                                                 \
            f32x2 D  = t3 * p;                                                  \
            float Rp = __builtin_amdgcn_rcpf(D.x * D.y);                        \
            f32x2 Rv = f32x2{D.y, D.x} * Rp;                                    \
            f32x2 gm = __builtin_elementwise_fma(P2L2E2, ug, NP2L2E2);          \
            f32x2 N  = __builtin_elementwise_fma(cs2[r], p, gm * t3);           \
            f32x2 c  = N * Rv;                                                  \
            cs2[r] = c;                                                         \
            f32x2 ec = exp2v(__builtin_elementwise_min(c, TH30));               \
            f32x2 t4 = ONE2 + uo, t5 = ONE2 + ec;                               \
            f32x2 qv = t4 * t5;                                                 \
            float Rq = __builtin_amdgcn_rcpf(qv.x * qv.y);                      \
            f32x2 R2 = f32x2{qv.y, qv.x} * Rq;                                  \
            f32x2 o  = t5 * R2;                                                 \
            f32x2 u2 = t4 * R2;                                                 \
            f32x2 tc = __builtin_elementwise_fma(NTWO2, u2, ONE2);              \
            h2[r] = o * tc;                                                     \
        }                                                                       \
        u32x4 bhv = {pk_bf16(h2[0].x, h2[1].x), pk_bf16(h2[2].x, h2[3].x),      \
                     pk_bf16(h2[0].y, h2[1].y), pk_bf16(h2[2].y, h2[3].y)};     \
        Bh = __builtin_bit_cast(bf16x8, bhv);                                   \
    } while (0)

    for (int w4 = 0; w4 < 128; ++w4) {
        const int nw = (w4 < 127) ? (w4 + 1) : 127;
        float4 na = xv[3 * nw + 0];
        float4 nb = xv[3 * nw + 1];
        float4 nc = xv[3 * nw + 2];

        STEP(xa.w, xb.x, xb.y);
        STEP(xb.z, xb.w, xc.x);
        STEP(xc.y, xc.z, xc.w);
        STEP(na.x, na.y, na.z);

        xa = na; xb = nb; xc = nc;
    }
#undef STEP

    // FC + sigmoid: lo units 4q+r (h2[r].x), hi units 16+4q+r (h2[r].y)
    float part = 0.f;
#pragma unroll
    for (int r = 0; r < 4; ++r) {
        part += W_fc[4 * q + r] * h2[r].x;
        part += W_fc[16 + 4 * q + r] * h2[r].y;
    }
    part += __shfl_xor(part, 16, 64);
    part += __shfl_xor(part, 32, 64);
    if (q == 0) {
        out[bn] = sigm(part + b_fc[0]);
    }
}

extern "C" void kernel_launch(void* const* d_in, const int* in_sizes, int n_in,
                              void* d_out, int out_size, void* d_ws, size_t ws_size,
                              hipStream_t stream) {
    const float* x    = (const float*)d_in[0];
    const float* W_ih = (const float*)d_in[1];
    const float* W_hh = (const float*)d_in[2];
    const float* b_ih = (const float*)d_in[3];
    const float* b_hh = (const float*)d_in[4];
    const float* W_fc = (const float*)d_in[5];
    const float* b_fc = (const float*)d_in[6];
    float* out        = (float*)d_out;

    const int n_groups = out_size / 16;      // 1024 waves
    const int n_blocks = (n_groups + 3) / 4; // 4 waves (256 threads) per block

    hipLaunchKernelGGL(lstm_mfma12_kernel, dim3(n_blocks), dim3(256), 0, stream,
                       x, W_ih, W_hh, b_ih, b_hh, W_fc, b_fc, out, n_groups);
}

// Round 13
// 293.233 us; speedup vs baseline: 1.1027x; 1.1027x over previous
//
#include <hip/hip_runtime.h>
#include <hip/hip_bf16.h>

typedef short bf16x8 __attribute__((ext_vector_type(8)));
typedef float f32x4 __attribute__((ext_vector_type(4)));
typedef unsigned int u32x4 __attribute__((ext_vector_type(4)));

#define MFMA(a, b, c) __builtin_amdgcn_mfma_f32_16x16x32_bf16((a), (b), (c), 0, 0, 0)

__device__ __forceinline__ unsigned short f2bf(float f) {
    unsigned u = __builtin_bit_cast(unsigned, f);
    unsigned r = u + 0x7FFFu + ((u >> 16) & 1u);   // RNE
    return (unsigned short)(r >> 16);
}

// pair of f32 -> packed bf16 dword (v_cvt_pk_bf16_f32)
__device__ __forceinline__ unsigned pk_bf16(float lo, float hi) {
    __hip_bfloat162 p = __float22bfloat162_rn(make_float2(lo, hi));
    unsigned r;
    __builtin_memcpy(&r, &p, sizeof(r));
    return r;
}

__device__ __forceinline__ float sigm(float x) {
    float e = __builtin_amdgcn_exp2f(-1.44269504088896f * x);
    return __builtin_amdgcn_rcpf(1.0f + e);
}

// R11 structure (best: 304us): one wave per 16 batches, lane-local recurrence,
// no barriers/LDS, loop-carried accx x-projection pipeline, common-denominator
// cell math (5 exp + 1 paired rcp per unit).
// NEW (R13): o*tanh(c) fused to a single fma:
//   h = sigm(zo)*tanh(c) = (ec - 1) / [(1+uo)(1+ec)] = fma(ec, R2, -R2)
//   with ec = 2^{c'} (c' = 2*log2e*c) and R2 = paired rcp((1+uo)(1+ec)).
//   Replaces the 4-op tail {o, u2, tc, h} of R11. Limits: c->-inf => -sigm(zo);
//   c clamped at 30 => error 2^-30. Scalar form (R12's f32x2 packing regressed).
__global__ __launch_bounds__(256, 1) void lstm_mfma13_kernel(
    const float* __restrict__ x,     // [B,512,3]
    const float* __restrict__ W_ih,  // [128,3]
    const float* __restrict__ W_hh,  // [128,32]
    const float* __restrict__ b_ih,  // [128]
    const float* __restrict__ b_hh,  // [128]
    const float* __restrict__ W_fc,  // [32]
    const float* __restrict__ b_fc,  // [1]
    float* __restrict__ out,         // [B]
    int n_groups)
{
    const int lane  = threadIdx.x & 63;
    const int wid   = threadIdx.x >> 6;
    const int group = blockIdx.x * 4 + wid;
    if (group >= n_groups) return;

    const int n = lane & 15;
    const int q = lane >> 4;

    const float NL2E  = -1.4426950408889634f;  // -log2(e)
    const float P2L2E =  2.8853900817779268f;  // +2*log2(e)

    // tiles: (0,1)=i, (2,3)=f, (4,5)=g, (6,7)=o ; even=units 0..15, odd=16..31
    bf16x8 A_hh[8], A_x[8];
#pragma unroll
    for (int t = 0; t < 8; ++t) {
        const int g = 16 * t + n;
        const float s = (t == 4 || t == 5) ? P2L2E : NL2E;
        bf16x8 a, ax;
#pragma unroll
        for (int j = 0; j < 8; ++j) {
            const int k = 16 * (j >> 2) + 4 * q + (j & 3);
            a[j] = (short)f2bf(s * W_hh[g * 32 + k]);
            float axv = 0.0f;
            if (q == 0 && j < 4) {
                axv = (j < 3) ? s * W_ih[g * 3 + j] : s * (b_ih[g] + b_hh[g]);
            }
            ax[j] = (short)f2bf(axv);
        }
        A_hh[t] = a;
        A_x[t]  = ax;
    }

    const long bn = (long)group * 16 + n;
    const float4* xv = (const float4*)(x + bn * (512L * 3));  // 384 float4/batch

    float cs[8] = {0.f, 0.f, 0.f, 0.f, 0.f, 0.f, 0.f, 0.f};
    float h[8]  = {0.f, 0.f, 0.f, 0.f, 0.f, 0.f, 0.f, 0.f};
    bf16x8 Bh = {0, 0, 0, 0, 0, 0, 0, 0};

    float4 xa = xv[0], xb = xv[1], xc = xv[2];

    // prologue: x-projection for step 0
    f32x4 accx[8];
    {
        unsigned bx01 = pk_bf16(xa.x, xa.y);
        unsigned bx23 = pk_bf16(xa.z, 1.0f);
        u32x4 bxv = {bx01, bx23, bx01, bx23};
        bf16x8 Bx = __builtin_bit_cast(bf16x8, bxv);
#pragma unroll
        for (int tt = 0; tt < 8; ++tt) {
            f32x4 z = {0.f, 0.f, 0.f, 0.f};
            accx[tt] = MFMA(A_x[tt], Bx, z);
        }
    }

#define STEP(XN0, XN1, XN2)                                                     \
    do {                                                                        \
        f32x4 acc[8];                                                           \
        _Pragma("unroll")                                                       \
        for (int tt = 0; tt < 8; ++tt) acc[tt] = MFMA(A_hh[tt], Bh, accx[tt]);  \
        unsigned bx01 = pk_bf16((XN0), (XN1));                                  \
        unsigned bx23 = pk_bf16((XN2), 1.0f);                                   \
        u32x4 bxv = {bx01, bx23, bx01, bx23};                                   \
        bf16x8 Bx = __builtin_bit_cast(bf16x8, bxv);                            \
        _Pragma("unroll")                                                       \
        for (int tt = 0; tt < 8; ++tt) {                                        \
            f32x4 z = {0.f, 0.f, 0.f, 0.f};                                     \
            accx[tt] = MFMA(A_x[tt], Bx, z);                                    \
        }                                                                       \
        _Pragma("unroll")                                                       \
        for (int r = 0; r < 4; ++r) {                                           \
            float ui0 = __builtin_amdgcn_exp2f(acc[0][r]);                      \
            float uf0 = __builtin_amdgcn_exp2f(acc[2][r]);                      \
            float ug0 = __builtin_amdgcn_exp2f(acc[4][r]);                      \
            float uo0 = __builtin_amdgcn_exp2f(acc[6][r]);                      \
            float ui1 = __builtin_amdgcn_exp2f(acc[1][r]);                      \
            float uf1 = __builtin_amdgcn_exp2f(acc[3][r]);                      \
            float ug1 = __builtin_amdgcn_exp2f(acc[5][r]);                      \
            float uo1 = __builtin_amdgcn_exp2f(acc[7][r]);                      \
            float t1_0 = 1.0f + ui0, t2_0 = 1.0f + ug0, t3_0 = 1.0f + uf0;      \
            float t1_1 = 1.0f + ui1, t2_1 = 1.0f + ug1, t3_1 = 1.0f + uf1;      \
            float p0 = t1_0 * t2_0, p1 = t1_1 * t2_1;                           \
            float D0 = t3_0 * p0,   D1 = t3_1 * p1;                             \
            float Rp = __builtin_amdgcn_rcpf(D0 * D1);                          \
            float R0 = D1 * Rp, R1 = D0 * Rp;                                   \
            float gm0 = fmaf(P2L2E, ug0, -P2L2E);                               \
            float gm1 = fmaf(P2L2E, ug1, -P2L2E);                               \
            float N0 = fmaf(cs[r],     p0, gm0 * t3_0);                         \
            float N1 = fmaf(cs[4 + r], p1, gm1 * t3_1);                         \
            float c0 = N0 * R0, c1 = N1 * R1;                                   \
            cs[r] = c0; cs[4 + r] = c1;                                         \
            float ec0 = __builtin_amdgcn_exp2f(fminf(c0, 30.0f));               \
            float ec1 = __builtin_amdgcn_exp2f(fminf(c1, 30.0f));               \
            float t4_0 = 1.0f + uo0, t5_0 = 1.0f + ec0;                         \
            float t4_1 = 1.0f + uo1, t5_1 = 1.0f + ec1;                         \
            float q0 = t4_0 * t5_0, q1 = t4_1 * t5_1;                           \
            float Rq = __builtin_amdgcn_rcpf(q0 * q1);                          \
            float R2_0 = q1 * Rq, R2_1 = q0 * Rq;                               \
            h[r]     = fmaf(ec0, R2_0, -R2_0);                                  \
            h[4 + r] = fmaf(ec1, R2_1, -R2_1);                                  \
        }                                                                       \
        u32x4 bhv = {pk_bf16(h[0], h[1]), pk_bf16(h[2], h[3]),                  \
                     pk_bf16(h[4], h[5]), pk_bf16(h[6], h[7])};                 \
        Bh = __builtin_bit_cast(bf16x8, bhv);                                   \
    } while (0)

    for (int w4 = 0; w4 < 128; ++w4) {
        const int nw = (w4 < 127) ? (w4 + 1) : 127;
        float4 na = xv[3 * nw + 0];
        float4 nb = xv[3 * nw + 1];
        float4 nc = xv[3 * nw + 2];

        STEP(xa.w, xb.x, xb.y);
        STEP(xb.z, xb.w, xc.x);
        STEP(xc.y, xc.z, xc.w);
        STEP(na.x, na.y, na.z);

        xa = na; xb = nb; xc = nc;
    }
#undef STEP

    // FC + sigmoid
    float part = 0.f;
#pragma unroll
    for (int r = 0; r < 4; ++r) {
        part += W_fc[4 * q + r] * h[r];
        part += W_fc[16 + 4 * q + r] * h[4 + r];
    }
    part += __shfl_xor(part, 16, 64);
    part += __shfl_xor(part, 32, 64);
    if (q == 0) {
        out[bn] = sigm(part + b_fc[0]);
    }
}

extern "C" void kernel_launch(void* const* d_in, const int* in_sizes, int n_in,
                              void* d_out, int out_size, void* d_ws, size_t ws_size,
                              hipStream_t stream) {
    const float* x    = (const float*)d_in[0];
    const float* W_ih = (const float*)d_in[1];
    const float* W_hh = (const float*)d_in[2];
    const float* b_ih = (const float*)d_in[3];
    const float* b_hh = (const float*)d_in[4];
    const float* W_fc = (const float*)d_in[5];
    const float* b_fc = (const float*)d_in[6];
    float* out        = (float*)d_out;

    const int n_groups = out_size / 16;      // 1024 waves
    const int n_blocks = (n_groups + 3) / 4; // 4 waves (256 threads) per block

    hipLaunchKernelGGL(lstm_mfma13_kernel, dim3(n_blocks), dim3(256), 0, stream,
                       x, W_ih, W_hh, b_ih, b_hh, W_fc, b_fc, out, n_groups);
}